// Round 1
// baseline (334.707 us; speedup 1.0000x reference)
//
#include <hip/hip_runtime.h>

// CG tensor-product: Fs (256, 576, 2) f32, W (565248,) f32 -> out (256, 1152, 2) f32
// Fused per (l, z) block: per triple, stage1 computes FF[mc][ts] into LDS,
// stage2 accumulates out[mc][o] += FF[mc][ts] * W[ts][o] in registers.

#define NL 6

__constant__ int d_NTRI[NL]      = {6,10,13,14,14,12};
__constant__ int d_TRI_START[NL] = {0,6,16,29,43,57};
__constant__ int d_TRI_L1[69] = {
  0,1,2,3,4,5,
  0,1,1,2,2,3,3,4,4,5,
  0,1,1,1,2,2,2,3,3,3,4,4,5,
  0,1,1,1,2,2,2,2,3,3,3,4,4,5,
  0,1,1,1,2,2,2,2,3,3,3,4,4,5,
  0,1,1,2,2,2,3,3,3,4,4,5};
__constant__ int d_TRI_L2[69] = {
  0,1,2,3,4,5,
  1,1,2,2,3,3,4,4,5,5,
  2,1,2,3,2,3,4,3,4,5,4,5,5,
  3,2,3,4,2,3,4,5,3,4,5,4,5,5,
  4,3,4,5,2,3,4,5,3,4,5,4,5,5,
  5,4,5,3,4,5,3,4,5,4,5,5};
__constant__ int d_CUM_F[NL]   = {0,16,64,144,256,400};
__constant__ int d_CUM_W[NL]   = {0,49152,131072,237568,352256,466944};
__constant__ int d_OUT_OFF[NL] = {0,32,128,288,512,800};

__constant__ double d_FACT[17] = {
  1.0,1.0,2.0,6.0,24.0,120.0,720.0,5040.0,40320.0,362880.0,
  3628800.0,39916800.0,479001600.0,6227020800.0,87178291200.0,
  1307674368000.0,20922789888000.0};

__device__ __forceinline__ int imax(int a, int b){ return a > b ? a : b; }
__device__ __forceinline__ int imin(int a, int b){ return a < b ? a : b; }

__device__ float cg_coef(int l1, int m1, int l2, int m2, int l, int m) {
  // Racah formula, Condon-Shortley, exact double factorials (max 16!)
  double pre = sqrt((double)(2*l+1) * d_FACT[l+l1-l2] * d_FACT[l-l1+l2] *
                    d_FACT[l1+l2-l] / d_FACT[l1+l2+l+1]);
  pre *= sqrt(d_FACT[l+m]*d_FACT[l-m]*d_FACT[l1-m1]*d_FACT[l1+m1]*
              d_FACT[l2-m2]*d_FACT[l2+m2]);
  int kmin = imax(0, imax(l2 - l - m1, l1 + m2 - l));
  int kmax = imin(l1 + l2 - l, imin(l1 - m1, l2 + m2));
  double s = 0.0;
  for (int k = kmin; k <= kmax; ++k) {
    double d = d_FACT[k]*d_FACT[l1+l2-l-k]*d_FACT[l1-m1-k]*d_FACT[l2+m2-k]*
               d_FACT[l-l2+m1+k]*d_FACT[l-l1-m2+k];
    s += ((k & 1) ? -1.0 : 1.0) / d;
  }
  return (float)(pre * s);
}

__global__ __launch_bounds__(256)
void cgbn_fused(const float* __restrict__ Fs, const float* __restrict__ W,
                float* __restrict__ out) {
  const int l   = blockIdx.x;   // 0..5
  const int z   = blockIdx.y;   // 0..255
  const int tid = threadIdx.x;  // 0..255

  __shared__ float sF1[11*32];
  __shared__ float sF2[11*32];
  __shared__ float sFF[24*256];       // [mc][ts], mc = m*2+c (rows beyond R are junk)
  __shared__ float sCG[14*121];       // [ti][m(11)][m1(11)]

  const int ntri = d_NTRI[l];
  const int tst  = d_TRI_START[l];

  // ---- per-block CG table (fp64 Racah, once) ----
  for (int idx = tid; idx < ntri * 121; idx += 256) {
    int ti  = idx / 121;
    int rem = idx - ti * 121;
    int mi  = rem / 11;
    int m1i = rem - mi * 11;
    int l1 = d_TRI_L1[tst + ti], l2 = d_TRI_L2[tst + ti];
    float v = 0.f;
    if (mi <= 2*l && m1i <= 2*l1) {
      int m = mi - l, m1 = m1i - l1, m2 = m - m1;
      if (m2 >= -l2 && m2 <= l2) v = cg_coef(l1, m1, l2, m2, l, m);
    }
    sCG[idx] = v;
  }

  const int tt = tid >> 4;   // t 0..15
  const int ss = tid & 15;   // s 0..15
  const int r0 = tid >> 5;   // row group 0..7
  const int oo = tid & 31;   // output column 0..31

  float acc0 = 0.f, acc1 = 0.f, acc2 = 0.f;

  const int twoLp1 = 2*l + 1;
  const int R = twoLp1 * 2;          // valid rows in sFF
  const float* FsZ = Fs + (size_t)z * (576*2);

  for (int ti = 0; ti < ntri; ++ti) {
    const int l1 = d_TRI_L1[tst + ti], l2 = d_TRI_L2[tst + ti];
    const int n1 = (2*l1 + 1) * 32, n2 = (2*l2 + 1) * 32;

    __syncthreads();  // prior stage2 done before overwriting sF1/sF2/sFF
    for (int i = tid; i < n1; i += 256) sF1[i] = FsZ[d_CUM_F[l1]*2 + i];
    for (int i = tid; i < n2; i += 256) sF2[i] = FsZ[d_CUM_F[l2]*2 + i];
    __syncthreads();

    // ---- stage 1: FF[m][t][s] (complex) for this triple ----
    for (int mi = 0; mi < twoLp1; ++mi) {
      const int m  = mi - l;
      const int lo = imax(-l1, m - l2), hi = imin(l1, m + l2);
      float ar = 0.f, ai = 0.f;
      for (int m1 = lo; m1 <= hi; ++m1) {
        const float cg  = sCG[ti*121 + mi*11 + (m1 + l1)];
        const int   a   = (m1 + l1) * 32 + tt * 2;
        const int   b   = ((m - m1) + l2) * 32 + ss * 2;
        const float f1r = sF1[a],     f1i = sF1[a + 1];
        const float f2r = sF2[b],     f2i = sF2[b + 1];
        ar = fmaf(cg, f1r*f2r - f1i*f2i, ar);
        ai = fmaf(cg, f1r*f2i + f1i*f2r, ai);
      }
      sFF[(2*mi    ) * 256 + tid] = ar;
      sFF[(2*mi + 1) * 256 + tid] = ai;
    }
    __syncthreads();

    // ---- stage 2: acc[row][o] += FF[row][k] * W[k][o] ----
    const float* wp  = W + d_CUM_W[l] + ti * 8192 + oo;
    const float* fr0 = sFF + (r0     ) * 256;
    const float* fr1 = sFF + (r0 + 8 ) * 256;
    const float* fr2 = sFF + (r0 + 16) * 256;
    #pragma unroll 4
    for (int k = 0; k < 256; ++k) {
      const float w = wp[k * 32];
      acc0 = fmaf(fr0[k], w, acc0);
      acc1 = fmaf(fr1[k], w, acc1);
      acc2 = fmaf(fr2[k], w, acc2);
    }
  }

  // ---- write out ----
  const float accs[3] = {acc0, acc1, acc2};
  #pragma unroll
  for (int j = 0; j < 3; ++j) {
    const int row = r0 + 8*j;
    if (row < R) {
      const int m = row >> 1, c = row & 1;
      out[((size_t)z * 1152 + d_OUT_OFF[l] + m * 32 + oo) * 2 + c] = accs[j];
    }
  }
}

extern "C" void kernel_launch(void* const* d_in, const int* in_sizes, int n_in,
                              void* d_out, int out_size, void* d_ws, size_t ws_size,
                              hipStream_t stream) {
  const float* Fs = (const float*)d_in[0];
  const float* W  = (const float*)d_in[1];
  float* out = (float*)d_out;
  dim3 grid(6, 256);
  dim3 block(256);
  hipLaunchKernelGGL(cgbn_fused, grid, block, 0, stream, Fs, W, out);
}

// Round 2
// 152.660 us; speedup vs baseline: 2.1925x; 2.1925x over previous
//
#include <hip/hip_runtime.h>

// CG tensor product, 3-kernel MFMA design:
//  k0: W (f32, [l][k][o]) -> Wt bf16 [l][o][k]   (ws)
//  k1<L>: stage-1 CG contraction -> FF bf16 [l][(z,m,c) row][k]  (ws)
//  k2: per-l GEMM out[row, o] = sum_k FF[row,k] * Wt[o,k] via mfma 16x16x32 bf16
// Fallback to the round-1 fused VALU kernel if ws_size is too small.

#define NL 6

__constant__ int d_NTRI[NL]      = {6,10,13,14,14,12};
__constant__ int d_TRI_START[NL] = {0,6,16,29,43,57};
__constant__ int d_TRI_L1[69] = {
  0,1,2,3,4,5,
  0,1,1,2,2,3,3,4,4,5,
  0,1,1,1,2,2,2,3,3,3,4,4,5,
  0,1,1,1,2,2,2,2,3,3,3,4,4,5,
  0,1,1,1,2,2,2,2,3,3,3,4,4,5,
  0,1,1,2,2,2,3,3,3,4,4,5};
__constant__ int d_TRI_L2[69] = {
  0,1,2,3,4,5,
  1,1,2,2,3,3,4,4,5,5,
  2,1,2,3,2,3,4,3,4,5,4,5,5,
  3,2,3,4,2,3,4,5,3,4,5,4,5,5,
  4,3,4,5,2,3,4,5,3,4,5,4,5,5,
  5,4,5,3,4,5,3,4,5,4,5,5};
__constant__ int d_CUM_F[NL]   = {0,16,64,144,256,400};
__constant__ int d_CUM_W[NL]   = {0,49152,131072,237568,352256,466944};
__constant__ int d_OUT_OFF[NL] = {0,32,128,288,512,800};
// FF offsets in ws (bf16 elements), after Wt (565248 elems)
__constant__ int d_FF_OFF[NL]  = {565248,1351680,5283840,13803520,26648576,43163648};
// total ws need: 60465152 bf16 elems = 120930304 bytes

__constant__ double d_FACT[17] = {
  1.0,1.0,2.0,6.0,24.0,120.0,720.0,5040.0,40320.0,362880.0,
  3628800.0,39916800.0,479001600.0,6227020800.0,87178291200.0,
  1307674368000.0,20922789888000.0};

__device__ __forceinline__ int imax(int a, int b){ return a > b ? a : b; }
__device__ __forceinline__ int imin(int a, int b){ return a < b ? a : b; }

__device__ __forceinline__ constexpr int cumf(int l) {
  return l==0?0 : l==1?16 : l==2?64 : l==3?144 : l==4?256 : 400;
}

__device__ float cg_coef(int l1, int m1, int l2, int m2, int l, int m) {
  double pre = sqrt((double)(2*l+1) * d_FACT[l+l1-l2] * d_FACT[l-l1+l2] *
                    d_FACT[l1+l2-l] / d_FACT[l1+l2+l+1]);
  pre *= sqrt(d_FACT[l+m]*d_FACT[l-m]*d_FACT[l1-m1]*d_FACT[l1+m1]*
              d_FACT[l2-m2]*d_FACT[l2+m2]);
  int kmin = imax(0, imax(l2 - l - m1, l1 + m2 - l));
  int kmax = imin(l1 + l2 - l, imin(l1 - m1, l2 + m2));
  double s = 0.0;
  for (int k = kmin; k <= kmax; ++k) {
    double d = d_FACT[k]*d_FACT[l1+l2-l-k]*d_FACT[l1-m1-k]*d_FACT[l2+m2-k]*
               d_FACT[l-l2+m1+k]*d_FACT[l-l1-m2+k];
    s += ((k & 1) ? -1.0 : 1.0) / d;
  }
  return (float)(pre * s);
}

__device__ __forceinline__ unsigned short f2bf(float x) {
  unsigned int u = __float_as_uint(x);
  unsigned int r = (u + 0x7FFFu + ((u >> 16) & 1u)) >> 16;
  return (unsigned short)r;
}

using bf16x8 = __attribute__((ext_vector_type(8))) short;
using f32x4  = __attribute__((ext_vector_type(4))) float;

// ---------------- k0: W f32 [k][o] -> Wt bf16 [o][k] ----------------
__global__ __launch_bounds__(256)
void k0_wt(const float* __restrict__ W, unsigned short* __restrict__ ws) {
  const int l = blockIdx.y;
  const int n = d_NTRI[l] * 8192;           // T_FF*32 elements
  const int i = blockIdx.x * 256 + threadIdx.x;
  if (i >= n) return;
  const int Kl = 256 * d_NTRI[l];
  const int k = i >> 5, o = i & 31;
  ws[d_CUM_W[l] + (size_t)o * Kl + k] = f2bf(W[d_CUM_W[l] + i]);
}

// ---------------- k1: stage-1 CG contraction -> FF bf16 ----------------
template<int L, int L1, int L2>
__device__ __forceinline__ void tri_body(int z, const float* __restrict__ Fs,
                                         unsigned short* __restrict__ FFl,
                                         int Kl, int kb, float* sCG) {
  const int tid = threadIdx.x;
  constexpr int N1 = 2*L1+1, N2 = 2*L2+1, NM = 2*L+1;
  for (int idx = tid; idx < NM*N1; idx += 256) {
    int mi = idx / N1, m1i = idx - mi*N1;
    int m2 = (mi - L) - (m1i - L1);
    sCG[idx] = (m2 >= -L2 && m2 <= L2) ? cg_coef(L1, m1i-L1, L2, m2, L, mi-L) : 0.f;
  }
  __syncthreads();
  const int t = tid >> 4, s = tid & 15;
  const float* FsZ = Fs + (size_t)z * 1152;
  float f1r[N1], f1i[N1], f2r[N2], f2i[N2];
  #pragma unroll
  for (int a = 0; a < N1; ++a) {
    const float* p = FsZ + (cumf(L1) + a*16 + t) * 2;
    f1r[a] = p[0]; f1i[a] = p[1];
  }
  #pragma unroll
  for (int b = 0; b < N2; ++b) {
    const float* p = FsZ + (cumf(L2) + b*16 + s) * 2;
    f2r[b] = p[0]; f2i[b] = p[1];
  }
  #pragma unroll
  for (int mi = 0; mi < NM; ++mi) {
    float ar = 0.f, ai = 0.f;
    #pragma unroll
    for (int m1i = 0; m1i < N1; ++m1i) {
      const int m2i = (mi - L) - (m1i - L1) + L2;   // folds to constant after unroll
      if (m2i >= 0 && m2i < N2) {
        const float cg = sCG[mi*N1 + m1i];
        ar = fmaf(cg, f1r[m1i]*f2r[m2i] - f1i[m1i]*f2i[m2i], ar);
        ai = fmaf(cg, f1r[m1i]*f2i[m2i] + f1i[m1i]*f2r[m2i], ai);
      }
    }
    const size_t row = ((size_t)z * NM + mi) * 2;
    FFl[row * Kl + kb + tid]       = f2bf(ar);
    FFl[(row + 1) * Kl + kb + tid] = f2bf(ai);
  }
}

#define TRI_CASE(A,B) \
  case (A*8+B): if constexpr ((B - A) <= L && L <= (A + B)) { \
    tri_body<L,A,B>(z, Fs, FFl, Kl, kb, sCG); } break;

template<int L>
__global__ __launch_bounds__(256)
void k1_ff(const float* __restrict__ Fs, unsigned short* __restrict__ ws) {
  __shared__ float sCG[121];
  const int til = blockIdx.x, z = blockIdx.y;
  unsigned short* FFl = ws + (size_t)d_FF_OFF[L];
  const int Kl = 256 * d_NTRI[L];
  const int kb = til * 256;
  const int ti = d_TRI_START[L] + til;
  const int code = d_TRI_L1[ti] * 8 + d_TRI_L2[ti];
  switch (code) {
    TRI_CASE(0,0) TRI_CASE(0,1) TRI_CASE(0,2) TRI_CASE(0,3) TRI_CASE(0,4) TRI_CASE(0,5)
    TRI_CASE(1,1) TRI_CASE(1,2) TRI_CASE(1,3) TRI_CASE(1,4) TRI_CASE(1,5)
    TRI_CASE(2,2) TRI_CASE(2,3) TRI_CASE(2,4) TRI_CASE(2,5)
    TRI_CASE(3,3) TRI_CASE(3,4) TRI_CASE(3,5)
    TRI_CASE(4,4) TRI_CASE(4,5)
    TRI_CASE(5,5)
    default: break;
  }
}

// ---------------- k2: per-l GEMM, mfma 16x16x32 bf16, no LDS ----------------
__global__ __launch_bounds__(128)
void k2_gemm(const unsigned short* __restrict__ ws, float* __restrict__ out) {
  const int l  = blockIdx.y;
  const int NM = 2*l + 1;
  const int Ml = 512 * NM;
  const int tile = blockIdx.x;
  if (tile * 32 >= Ml) return;
  const int Kl = 256 * d_NTRI[l];
  const unsigned short* A  = ws + (size_t)d_FF_OFF[l];
  const unsigned short* Bt = ws + (size_t)d_CUM_W[l];
  const int lane = threadIdx.x & 63;
  const int wv   = threadIdx.x >> 6;        // 0..1
  const int col  = lane & 15;
  const int kof  = (lane >> 4) * 8;
  const int rA   = tile*32 + wv*16 + col;
  const bf16x8* pa  = (const bf16x8*)(A  + (size_t)rA * Kl + kof);
  const bf16x8* pb0 = (const bf16x8*)(Bt + (size_t)col * Kl + kof);
  const bf16x8* pb1 = (const bf16x8*)(Bt + (size_t)(col + 16) * Kl + kof);
  f32x4 acc0 = {0.f,0.f,0.f,0.f}, acc1 = {0.f,0.f,0.f,0.f};
  const int nk = Kl >> 5;
  #pragma unroll 4
  for (int kk = 0; kk < nk; ++kk) {
    bf16x8 av = pa[kk*4];
    bf16x8 b0 = pb0[kk*4];
    bf16x8 b1 = pb1[kk*4];
    acc0 = __builtin_amdgcn_mfma_f32_16x16x32_bf16(av, b0, acc0, 0, 0, 0);
    acc1 = __builtin_amdgcn_mfma_f32_16x16x32_bf16(av, b1, acc1, 0, 0, 0);
  }
  // epilogue: D row = (lane>>4)*4 + j, col = lane&15 (+16 for acc1)
  const int R2 = 2 * NM;
  const int rbase = tile*32 + wv*16 + (lane >> 4) * 4;
  int z   = rbase / R2;
  int rem = rbase - z * R2;
  const int oo = d_OUT_OFF[l];
  #pragma unroll
  for (int j = 0; j < 4; ++j) {
    const int mi = rem >> 1, c = rem & 1;
    float* po = out + ((size_t)z * 1152 + oo + mi * 32) * 2 + c;
    po[col * 2]        = acc0[j];
    po[(col + 16) * 2] = acc1[j];
    if (++rem == R2) { rem = 0; ++z; }
  }
}

// ---------------- fallback: round-1 fused kernel ----------------
__global__ __launch_bounds__(256)
void cgbn_fused(const float* __restrict__ Fs, const float* __restrict__ W,
                float* __restrict__ out) {
  const int l   = blockIdx.x;
  const int z   = blockIdx.y;
  const int tid = threadIdx.x;

  __shared__ float sF1[11*32];
  __shared__ float sF2[11*32];
  __shared__ float sFF[24*256];
  __shared__ float sCG[14*121];

  const int ntri = d_NTRI[l];
  const int tst  = d_TRI_START[l];

  for (int idx = tid; idx < ntri * 121; idx += 256) {
    int ti  = idx / 121;
    int rem = idx - ti * 121;
    int mi  = rem / 11;
    int m1i = rem - mi * 11;
    int l1 = d_TRI_L1[tst + ti], l2 = d_TRI_L2[tst + ti];
    float v = 0.f;
    if (mi <= 2*l && m1i <= 2*l1) {
      int m = mi - l, m1 = m1i - l1, m2 = m - m1;
      if (m2 >= -l2 && m2 <= l2) v = cg_coef(l1, m1, l2, m2, l, m);
    }
    sCG[idx] = v;
  }

  const int tt = tid >> 4;
  const int ss = tid & 15;
  const int r0 = tid >> 5;
  const int oo = tid & 31;

  float acc0 = 0.f, acc1 = 0.f, acc2 = 0.f;

  const int twoLp1 = 2*l + 1;
  const int R = twoLp1 * 2;
  const float* FsZ = Fs + (size_t)z * (576*2);

  for (int ti = 0; ti < ntri; ++ti) {
    const int l1 = d_TRI_L1[tst + ti], l2 = d_TRI_L2[tst + ti];
    const int n1 = (2*l1 + 1) * 32, n2 = (2*l2 + 1) * 32;

    __syncthreads();
    for (int i = tid; i < n1; i += 256) sF1[i] = FsZ[d_CUM_F[l1]*2 + i];
    for (int i = tid; i < n2; i += 256) sF2[i] = FsZ[d_CUM_F[l2]*2 + i];
    __syncthreads();

    for (int mi = 0; mi < twoLp1; ++mi) {
      const int m  = mi - l;
      const int lo = imax(-l1, m - l2), hi = imin(l1, m + l2);
      float ar = 0.f, ai = 0.f;
      for (int m1 = lo; m1 <= hi; ++m1) {
        const float cg  = sCG[ti*121 + mi*11 + (m1 + l1)];
        const int   a   = (m1 + l1) * 32 + tt * 2;
        const int   b   = ((m - m1) + l2) * 32 + ss * 2;
        const float f1r = sF1[a],     f1i = sF1[a + 1];
        const float f2r = sF2[b],     f2i = sF2[b + 1];
        ar = fmaf(cg, f1r*f2r - f1i*f2i, ar);
        ai = fmaf(cg, f1r*f2i + f1i*f2r, ai);
      }
      sFF[(2*mi    ) * 256 + tid] = ar;
      sFF[(2*mi + 1) * 256 + tid] = ai;
    }
    __syncthreads();

    const float* wp  = W + d_CUM_W[l] + ti * 8192 + oo;
    const float* fr0 = sFF + (r0     ) * 256;
    const float* fr1 = sFF + (r0 + 8 ) * 256;
    const float* fr2 = sFF + (r0 + 16) * 256;
    #pragma unroll 4
    for (int k = 0; k < 256; ++k) {
      const float w = wp[k * 32];
      acc0 = fmaf(fr0[k], w, acc0);
      acc1 = fmaf(fr1[k], w, acc1);
      acc2 = fmaf(fr2[k], w, acc2);
    }
  }

  const float accs[3] = {acc0, acc1, acc2};
  #pragma unroll
  for (int j = 0; j < 3; ++j) {
    const int row = r0 + 8*j;
    if (row < R) {
      const int m = row >> 1, c = row & 1;
      out[((size_t)z * 1152 + d_OUT_OFF[l] + m * 32 + oo) * 2 + c] = accs[j];
    }
  }
}

extern "C" void kernel_launch(void* const* d_in, const int* in_sizes, int n_in,
                              void* d_out, int out_size, void* d_ws, size_t ws_size,
                              hipStream_t stream) {
  const float* Fs = (const float*)d_in[0];
  const float* W  = (const float*)d_in[1];
  float* out = (float*)d_out;

  if (ws_size >= 120930304ULL) {
    unsigned short* ws = (unsigned short*)d_ws;
    hipLaunchKernelGGL(k0_wt, dim3(448, 6), dim3(256), 0, stream, W, ws);
    hipLaunchKernelGGL(k1_ff<0>, dim3(6,  256), dim3(256), 0, stream, Fs, ws);
    hipLaunchKernelGGL(k1_ff<1>, dim3(10, 256), dim3(256), 0, stream, Fs, ws);
    hipLaunchKernelGGL(k1_ff<2>, dim3(13, 256), dim3(256), 0, stream, Fs, ws);
    hipLaunchKernelGGL(k1_ff<3>, dim3(14, 256), dim3(256), 0, stream, Fs, ws);
    hipLaunchKernelGGL(k1_ff<4>, dim3(14, 256), dim3(256), 0, stream, Fs, ws);
    hipLaunchKernelGGL(k1_ff<5>, dim3(12, 256), dim3(256), 0, stream, Fs, ws);
    hipLaunchKernelGGL(k2_gemm, dim3(176, 6), dim3(128), 0, stream, ws, out);
  } else {
    hipLaunchKernelGGL(cgbn_fused, dim3(6, 256), dim3(256), 0, stream, Fs, W, out);
  }
}

// Round 3
// 118.283 us; speedup vs baseline: 2.8297x; 1.2906x over previous
//
#include <hip/hip_runtime.h>

// CG tensor product, 4-launch MFMA design:
//  k0:      W (f32, [l][k][o]) -> Wt bf16 [l][o][k]        (ws)
//  k1_all:  stage-1 CG contraction -> FF bf16 [l][row][k]  (ws), one launch,
//           grid (69 triples, 64 z-quads), 8B vectorized stores
//  zero_out + k2_gemm: per-l GEMM out = FF * Wt^T via mfma 16x16x32 bf16,
//           split-K x4 with f32 atomicAdd epilogue
// Fallback to the round-1 fused VALU kernel if ws_size is too small.

#define NL 6

__constant__ int d_NTRI[NL]      = {6,10,13,14,14,12};
__constant__ int d_TRI_START[NL] = {0,6,16,29,43,57};
__constant__ int d_TRI_L1[69] = {
  0,1,2,3,4,5,
  0,1,1,2,2,3,3,4,4,5,
  0,1,1,1,2,2,2,3,3,3,4,4,5,
  0,1,1,1,2,2,2,2,3,3,3,4,4,5,
  0,1,1,1,2,2,2,2,3,3,3,4,4,5,
  0,1,1,2,2,2,3,3,3,4,4,5};
__constant__ int d_TRI_L2[69] = {
  0,1,2,3,4,5,
  1,1,2,2,3,3,4,4,5,5,
  2,1,2,3,2,3,4,3,4,5,4,5,5,
  3,2,3,4,2,3,4,5,3,4,5,4,5,5,
  4,3,4,5,2,3,4,5,3,4,5,4,5,5,
  5,4,5,3,4,5,3,4,5,4,5,5};
__constant__ int d_TRI_L[69] = {
  0,0,0,0,0,0,
  1,1,1,1,1,1,1,1,1,1,
  2,2,2,2,2,2,2,2,2,2,2,2,2,
  3,3,3,3,3,3,3,3,3,3,3,3,3,3,
  4,4,4,4,4,4,4,4,4,4,4,4,4,4,
  5,5,5,5,5,5,5,5,5,5,5,5};
__constant__ int d_TRI_TIL[69] = {
  0,1,2,3,4,5,
  0,1,2,3,4,5,6,7,8,9,
  0,1,2,3,4,5,6,7,8,9,10,11,12,
  0,1,2,3,4,5,6,7,8,9,10,11,12,13,
  0,1,2,3,4,5,6,7,8,9,10,11,12,13,
  0,1,2,3,4,5,6,7,8,9,10,11};
__constant__ int d_CUM_F[NL]   = {0,16,64,144,256,400};
__constant__ int d_CUM_W[NL]   = {0,49152,131072,237568,352256,466944};
__constant__ int d_OUT_OFF[NL] = {0,32,128,288,512,800};
// FF offsets in ws (bf16 elements), after Wt (565248 elems)
__constant__ int d_FF_OFF[NL]  = {565248,1351680,5283840,13803520,26648576,43163648};
// total ws need: 60465152 bf16 elems = 120930304 bytes

__constant__ double d_FACT[17] = {
  1.0,1.0,2.0,6.0,24.0,120.0,720.0,5040.0,40320.0,362880.0,
  3628800.0,39916800.0,479001600.0,6227020800.0,87178291200.0,
  1307674368000.0,20922789888000.0};

__device__ __forceinline__ int imax(int a, int b){ return a > b ? a : b; }
__device__ __forceinline__ int imin(int a, int b){ return a < b ? a : b; }

__device__ __forceinline__ constexpr int cumf(int l) {
  return l==0?0 : l==1?16 : l==2?64 : l==3?144 : l==4?256 : 400;
}

__device__ float cg_coef(int l1, int m1, int l2, int m2, int l, int m) {
  double pre = sqrt((double)(2*l+1) * d_FACT[l+l1-l2] * d_FACT[l-l1+l2] *
                    d_FACT[l1+l2-l] / d_FACT[l1+l2+l+1]);
  pre *= sqrt(d_FACT[l+m]*d_FACT[l-m]*d_FACT[l1-m1]*d_FACT[l1+m1]*
              d_FACT[l2-m2]*d_FACT[l2+m2]);
  int kmin = imax(0, imax(l2 - l - m1, l1 + m2 - l));
  int kmax = imin(l1 + l2 - l, imin(l1 - m1, l2 + m2));
  double s = 0.0;
  for (int k = kmin; k <= kmax; ++k) {
    double d = d_FACT[k]*d_FACT[l1+l2-l-k]*d_FACT[l1-m1-k]*d_FACT[l2+m2-k]*
               d_FACT[l-l2+m1+k]*d_FACT[l-l1-m2+k];
    s += ((k & 1) ? -1.0 : 1.0) / d;
  }
  return (float)(pre * s);
}

__device__ __forceinline__ unsigned short f2bf(float x) {
  unsigned int u = __float_as_uint(x);
  unsigned int r = (u + 0x7FFFu + ((u >> 16) & 1u)) >> 16;
  return (unsigned short)r;
}

using bf16x8 = __attribute__((ext_vector_type(8))) short;
using f32x4  = __attribute__((ext_vector_type(4))) float;
using u16x4  = __attribute__((ext_vector_type(4))) unsigned short;

// ---------------- k0: W f32 [k][o] -> Wt bf16 [o][k] ----------------
__global__ __launch_bounds__(256)
void k0_wt(const float* __restrict__ W, unsigned short* __restrict__ ws) {
  const int l = blockIdx.y;
  const int n = d_NTRI[l] * 8192;
  const int i = blockIdx.x * 256 + threadIdx.x;
  if (i >= n) return;
  const int Kl = 256 * d_NTRI[l];
  const int k = i >> 5, o = i & 31;
  ws[d_CUM_W[l] + (size_t)o * Kl + k] = f2bf(W[d_CUM_W[l] + i]);
}

// ---------------- k1_all: stage-1 CG contraction -> FF bf16 ----------------
// wave = one z; thread (t = lane&15, h = lane>>4) owns s = h*4 .. h*4+3.
template<int L, int L1, int L2>
__device__ __forceinline__ void tri1(int z, const float* __restrict__ Fs,
                                     unsigned short* __restrict__ FFl,
                                     int Kl, int kb,
                                     const float* __restrict__ sCG) {
  constexpr int N1 = 2*L1+1, N2 = 2*L2+1, NM = 2*L+1;
  const int lane = threadIdx.x & 63;
  const int t = lane & 15, h = lane >> 4;
  const float* FsZ = Fs + (size_t)z * 1152;

  float f1r[N1], f1i[N1];
  #pragma unroll
  for (int a = 0; a < N1; ++a) {
    const float2 v = *(const float2*)(FsZ + (cumf(L1) + a*16 + t) * 2);
    f1r[a] = v.x; f1i[a] = v.y;
  }
  float f2r[N2][4], f2i[N2][4];
  #pragma unroll
  for (int b = 0; b < N2; ++b) {
    #pragma unroll
    for (int j = 0; j < 4; ++j) {
      const float2 v = *(const float2*)(FsZ + (cumf(L2) + b*16 + h*4 + j) * 2);
      f2r[b][j] = v.x; f2i[b][j] = v.y;
    }
  }

  #pragma unroll
  for (int mi = 0; mi < NM; ++mi) {
    float ar[4] = {0.f,0.f,0.f,0.f}, ai[4] = {0.f,0.f,0.f,0.f};
    #pragma unroll
    for (int m1i = 0; m1i < N1; ++m1i) {
      const int m2i = (mi - L) - (m1i - L1) + L2;  // compile-time per instance
      if (m2i >= 0 && m2i < N2) {
        const float cg = sCG[mi*N1 + m1i];
        #pragma unroll
        for (int j = 0; j < 4; ++j) {
          ar[j] = fmaf(cg, f1r[m1i]*f2r[m2i][j] - f1i[m1i]*f2i[m2i][j], ar[j]);
          ai[j] = fmaf(cg, f1r[m1i]*f2i[m2i][j] + f1i[m1i]*f2r[m2i][j], ai[j]);
        }
      }
    }
    u16x4 vr, vi;
    #pragma unroll
    for (int j = 0; j < 4; ++j) { vr[j] = f2bf(ar[j]); vi[j] = f2bf(ai[j]); }
    const size_t row = ((size_t)z * NM + mi) * 2;
    *(u16x4*)(FFl + row * Kl + kb + t*16 + h*4)       = vr;
    *(u16x4*)(FFl + (row + 1) * Kl + kb + t*16 + h*4) = vi;
  }
}

#define C3(GI,LL,A,B) case GI: tri1<LL,A,B>(z, Fs, FFl, Kl, kb, sCG); break;

__global__ __launch_bounds__(256)
void k1_all(const float* __restrict__ Fs, unsigned short* __restrict__ ws) {
  __shared__ float sCG[121];
  const int gi  = blockIdx.x;            // global triple 0..68
  const int tid = threadIdx.x;
  const int l  = d_TRI_L[gi], l1 = d_TRI_L1[gi], l2 = d_TRI_L2[gi];
  const int NM = 2*l + 1, N1v = 2*l1 + 1;

  for (int idx = tid; idx < NM * N1v; idx += 256) {
    int mi = idx / N1v, m1i = idx - mi * N1v;
    int m2 = (mi - l) - (m1i - l1);
    sCG[idx] = (m2 >= -l2 && m2 <= l2) ? cg_coef(l1, m1i-l1, l2, m2, l, mi-l) : 0.f;
  }
  __syncthreads();

  const int z = blockIdx.y * 4 + (tid >> 6);
  unsigned short* FFl = ws + (size_t)d_FF_OFF[l];
  const int Kl = 256 * d_NTRI[l];
  const int kb = d_TRI_TIL[gi] * 256;

  switch (gi) {
    C3(0,0,0,0) C3(1,0,1,1) C3(2,0,2,2) C3(3,0,3,3) C3(4,0,4,4) C3(5,0,5,5)
    C3(6,1,0,1) C3(7,1,1,1) C3(8,1,1,2) C3(9,1,2,2) C3(10,1,2,3) C3(11,1,3,3)
    C3(12,1,3,4) C3(13,1,4,4) C3(14,1,4,5) C3(15,1,5,5)
    C3(16,2,0,2) C3(17,2,1,1) C3(18,2,1,2) C3(19,2,1,3) C3(20,2,2,2) C3(21,2,2,3)
    C3(22,2,2,4) C3(23,2,3,3) C3(24,2,3,4) C3(25,2,3,5) C3(26,2,4,4) C3(27,2,4,5)
    C3(28,2,5,5)
    C3(29,3,0,3) C3(30,3,1,2) C3(31,3,1,3) C3(32,3,1,4) C3(33,3,2,2) C3(34,3,2,3)
    C3(35,3,2,4) C3(36,3,2,5) C3(37,3,3,3) C3(38,3,3,4) C3(39,3,3,5) C3(40,3,4,4)
    C3(41,3,4,5) C3(42,3,5,5)
    C3(43,4,0,4) C3(44,4,1,3) C3(45,4,1,4) C3(46,4,1,5) C3(47,4,2,2) C3(48,4,2,3)
    C3(49,4,2,4) C3(50,4,2,5) C3(51,4,3,3) C3(52,4,3,4) C3(53,4,3,5) C3(54,4,4,4)
    C3(55,4,4,5) C3(56,4,5,5)
    C3(57,5,0,5) C3(58,5,1,4) C3(59,5,1,5) C3(60,5,2,3) C3(61,5,2,4) C3(62,5,2,5)
    C3(63,5,3,3) C3(64,5,3,4) C3(65,5,3,5) C3(66,5,4,4) C3(67,5,4,5) C3(68,5,5,5)
    default: break;
  }
}

// ---------------- zero_out ----------------
__global__ __launch_bounds__(256)
void zero_out(float4* __restrict__ out) {
  out[blockIdx.x * 256 + threadIdx.x] = make_float4(0.f, 0.f, 0.f, 0.f);
}

// ---------- k2: per-l GEMM, mfma 16x16x32 bf16, split-K x4, atomic epilogue ----------
__global__ __launch_bounds__(256)
void k2_gemm(const unsigned short* __restrict__ ws, float* __restrict__ out) {
  const int l  = blockIdx.y;
  const int kc = blockIdx.z;               // 0..3
  const int NM = 2*l + 1;
  const int Ml = 512 * NM;
  const int tile = blockIdx.x;             // BM = 64
  if (tile * 64 >= Ml) return;
  const int Kl = 256 * d_NTRI[l];
  const int nk  = Kl >> 5;                 // 8*ntri, divisible by 4
  const int cnk = nk >> 2;                 // 2*ntri
  const unsigned short* A  = ws + (size_t)d_FF_OFF[l];
  const unsigned short* Bt = ws + (size_t)d_CUM_W[l];
  const int lane = threadIdx.x & 63;
  const int wv   = threadIdx.x >> 6;       // 0..3
  const int col  = lane & 15;
  const int kof  = (lane >> 4) * 8;
  const int rA   = tile*64 + wv*16 + col;
  const bf16x8* pa  = (const bf16x8*)(A  + (size_t)rA * Kl + kof);
  const bf16x8* pb0 = (const bf16x8*)(Bt + (size_t)col * Kl + kof);
  const bf16x8* pb1 = (const bf16x8*)(Bt + (size_t)(col + 16) * Kl + kof);
  f32x4 acc0 = {0.f,0.f,0.f,0.f}, acc1 = {0.f,0.f,0.f,0.f};
  const int k0 = kc * cnk, k1e = k0 + cnk;
  #pragma unroll 4
  for (int kk = k0; kk < k1e; ++kk) {
    bf16x8 av = pa[kk*4];
    bf16x8 b0 = pb0[kk*4];
    bf16x8 b1 = pb1[kk*4];
    acc0 = __builtin_amdgcn_mfma_f32_16x16x32_bf16(av, b0, acc0, 0, 0, 0);
    acc1 = __builtin_amdgcn_mfma_f32_16x16x32_bf16(av, b1, acc1, 0, 0, 0);
  }
  const int R2 = 2 * NM;
  const int rbase = tile*64 + wv*16 + (lane >> 4) * 4;
  int z   = rbase / R2;
  int rem = rbase - z * R2;
  const int oo = d_OUT_OFF[l];
  #pragma unroll
  for (int j = 0; j < 4; ++j) {
    const int mi = rem >> 1, c = rem & 1;
    float* po = out + ((size_t)z * 1152 + oo + mi * 32) * 2 + c;
    atomicAdd(po + col * 2,        acc0[j]);
    atomicAdd(po + (col + 16) * 2, acc1[j]);
    if (++rem == R2) { rem = 0; ++z; }
  }
}

// ---------------- fallback: round-1 fused kernel ----------------
__global__ __launch_bounds__(256)
void cgbn_fused(const float* __restrict__ Fs, const float* __restrict__ W,
                float* __restrict__ out) {
  const int l   = blockIdx.x;
  const int z   = blockIdx.y;
  const int tid = threadIdx.x;

  __shared__ float sF1[11*32];
  __shared__ float sF2[11*32];
  __shared__ float sFF[24*256];
  __shared__ float sCG[14*121];

  const int ntri = d_NTRI[l];
  const int tst  = d_TRI_START[l];

  for (int idx = tid; idx < ntri * 121; idx += 256) {
    int ti  = idx / 121;
    int rem = idx - ti * 121;
    int mi  = rem / 11;
    int m1i = rem - mi * 11;
    int l1 = d_TRI_L1[tst + ti], l2 = d_TRI_L2[tst + ti];
    float v = 0.f;
    if (mi <= 2*l && m1i <= 2*l1) {
      int m = mi - l, m1 = m1i - l1, m2 = m - m1;
      if (m2 >= -l2 && m2 <= l2) v = cg_coef(l1, m1, l2, m2, l, m);
    }
    sCG[idx] = v;
  }

  const int tt = tid >> 4;
  const int ss = tid & 15;
  const int r0 = tid >> 5;
  const int oo = tid & 31;

  float acc0 = 0.f, acc1 = 0.f, acc2 = 0.f;

  const int twoLp1 = 2*l + 1;
  const int R = twoLp1 * 2;
  const float* FsZ = Fs + (size_t)z * (576*2);

  for (int ti = 0; ti < ntri; ++ti) {
    const int l1 = d_TRI_L1[tst + ti], l2 = d_TRI_L2[tst + ti];
    const int n1 = (2*l1 + 1) * 32, n2 = (2*l2 + 1) * 32;

    __syncthreads();
    for (int i = tid; i < n1; i += 256) sF1[i] = FsZ[d_CUM_F[l1]*2 + i];
    for (int i = tid; i < n2; i += 256) sF2[i] = FsZ[d_CUM_F[l2]*2 + i];
    __syncthreads();

    for (int mi = 0; mi < twoLp1; ++mi) {
      const int m  = mi - l;
      const int lo = imax(-l1, m - l2), hi = imin(l1, m + l2);
      float ar = 0.f, ai = 0.f;
      for (int m1 = lo; m1 <= hi; ++m1) {
        const float cg  = sCG[ti*121 + mi*11 + (m1 + l1)];
        const int   a   = (m1 + l1) * 32 + tt * 2;
        const int   b   = ((m - m1) + l2) * 32 + ss * 2;
        const float f1r = sF1[a],     f1i = sF1[a + 1];
        const float f2r = sF2[b],     f2i = sF2[b + 1];
        ar = fmaf(cg, f1r*f2r - f1i*f2i, ar);
        ai = fmaf(cg, f1r*f2i + f1i*f2r, ai);
      }
      sFF[(2*mi    ) * 256 + tid] = ar;
      sFF[(2*mi + 1) * 256 + tid] = ai;
    }
    __syncthreads();

    const float* wp  = W + d_CUM_W[l] + ti * 8192 + oo;
    const float* fr0 = sFF + (r0     ) * 256;
    const float* fr1 = sFF + (r0 + 8 ) * 256;
    const float* fr2 = sFF + (r0 + 16) * 256;
    #pragma unroll 4
    for (int k = 0; k < 256; ++k) {
      const float w = wp[k * 32];
      acc0 = fmaf(fr0[k], w, acc0);
      acc1 = fmaf(fr1[k], w, acc1);
      acc2 = fmaf(fr2[k], w, acc2);
    }
  }

  const float accs[3] = {acc0, acc1, acc2};
  #pragma unroll
  for (int j = 0; j < 3; ++j) {
    const int row = r0 + 8*j;
    if (row < R) {
      const int m = row >> 1, c = row & 1;
      out[((size_t)z * 1152 + d_OUT_OFF[l] + m * 32 + oo) * 2 + c] = accs[j];
    }
  }
}

extern "C" void kernel_launch(void* const* d_in, const int* in_sizes, int n_in,
                              void* d_out, int out_size, void* d_ws, size_t ws_size,
                              hipStream_t stream) {
  const float* Fs = (const float*)d_in[0];
  const float* W  = (const float*)d_in[1];
  float* out = (float*)d_out;

  if (ws_size >= 120930304ULL) {
    unsigned short* ws = (unsigned short*)d_ws;
    hipLaunchKernelGGL(zero_out, dim3(576), dim3(256), 0, stream, (float4*)out);
    hipLaunchKernelGGL(k0_wt, dim3(448, 6), dim3(256), 0, stream, W, ws);
    hipLaunchKernelGGL(k1_all, dim3(69, 64), dim3(256), 0, stream, Fs, ws);
    hipLaunchKernelGGL(k2_gemm, dim3(88, 6, 4), dim3(256), 0, stream, ws, out);
  } else {
    hipLaunchKernelGGL(cgbn_fused, dim3(6, 256), dim3(256), 0, stream, Fs, W, out);
  }
}